// Round 1
// 245.714 us; speedup vs baseline: 1.0267x; 1.0267x over previous
//
#include <hip/hip_runtime.h>

#define NN 4
#define TT 24
#define CC 4
#define NT 96            // NN*TT
#define HWP 65536        // 256*256
#define NSLOT 33         // 32 strip partials + 1 edge partial per (nt,c)
#define TBL_OFF (288 * NSLOT * 2)   // float offset of per-nt scale table in workspace
#define TBL_STRIDE 12               // sA[3], biasA, sB[3], biasB, nt2(bits), pad

// ================= L1: fused bilinear-shift + min/max partials =================
// Translation-only => D=floor(-tx), E=floor(-ty), wx, wy constant per image.
// grid = 6144 strip blocks (bc = bid>>4, 16-row strips) + 288 edge blocks.
// Strip blocks stage 17 rows x 272 cols (zero-padded, float4-aligned window),
// emit 16 output rows, and accumulate min/max over the VALID staged elements
// (idempotent across overlapping strips). Edge blocks sweep the rows/columns
// no strip window ever stages, so the union covers every pixel exactly.
__global__ __launch_bounds__(256) void k_shift_mm(const float* __restrict__ x,
                                                  const float* __restrict__ thetas,
                                                  float* __restrict__ out,
                                                  float* __restrict__ part) {
    __shared__ float lds[17][272];
    __shared__ float smin[4], smax[4];
    int bid = blockIdx.x;
    int tid = threadIdx.x;
    float vmin = 1e30f, vmax = -1e30f;

    if (bid < 6144) {
        int strip = bid & 15;
        int bc    = bid >> 4;        // 0..383
        int b     = bc >> 2;         // nt
        int c     = bc & 3;
        float tx = thetas[2 * b];
        float ty = thetas[2 * b + 1];
        int   D  = (int)floorf(-tx);
        int   E  = (int)floorf(-ty);
        float wx = -tx - (float)D;
        float wy = -ty - (float)E;
        int x_lo = (D - 4) & ~3;     // aligned window start
        int s    = (D - x_lo) - 4;   // uniform shift in [0,3]
        int i0   = strip * 16;
        int y_base = i0 + E;
        const float* img = x + (size_t)bc * HWP;
        bool trackmm = (c < 3);

        for (int t = tid; t < 17 * 68; t += 256) {
            int r = t / 68;
            int m = t - r * 68;
            int y = y_base + r;
            int sx4 = x_lo + 4 * m;
            float4 v = make_float4(0.f, 0.f, 0.f, 0.f);
            if ((unsigned)y < 256u && (unsigned)sx4 <= 252u) {
                v = *(const float4*)(img + y * 256 + sx4);
                if (trackmm) {
                    vmin = fminf(vmin, fminf(fminf(v.x, v.y), fminf(v.z, v.w)));
                    vmax = fmaxf(vmax, fmaxf(fmaxf(v.x, v.y), fmaxf(v.z, v.w)));
                }
            }
            *(float4*)&lds[r][4 * m] = v;
        }
        for (int off = 32; off > 0; off >>= 1) {
            vmin = fminf(vmin, __shfl_down(vmin, off));
            vmax = fmaxf(vmax, __shfl_down(vmax, off));
        }
        if ((tid & 63) == 0) { smin[tid >> 6] = vmin; smax[tid >> 6] = vmax; }
        __syncthreads();             // guards lds staging AND smin/smax
        if (tid == 0 && trackmm) {
            int ch = b * 3 + c;
            part[(ch * NSLOT + strip) * 2]     = fminf(fminf(smin[0], smin[1]), fminf(smin[2], smin[3]));
            part[(ch * NSLOT + strip) * 2 + 1] = fmaxf(fmaxf(smax[0], smax[1]), fmaxf(smax[2], smax[3]));
        }

        int w = tid >> 6, q = tid & 63;
        float* outp = out + (size_t)bc * HWP + (size_t)i0 * 256 + 4 * q;
        #pragma unroll
        for (int k = 0; k < 4; ++k) {
            int r = 4 * w + k;
            const float* L0 = &lds[r][4 * q + 4];
            const float* L1 = &lds[r + 1][4 * q + 4];
            float4 a0 = *(const float4*)(L0);
            float4 a1 = *(const float4*)(L0 + 4);
            float4 b0 = *(const float4*)(L1);
            float4 b1 = *(const float4*)(L1 + 4);
            float rr[8];
            rr[0] = a0.x + wy * (b0.x - a0.x);
            rr[1] = a0.y + wy * (b0.y - a0.y);
            rr[2] = a0.z + wy * (b0.z - a0.z);
            rr[3] = a0.w + wy * (b0.w - a0.w);
            rr[4] = a1.x + wy * (b1.x - a1.x);
            rr[5] = a1.y + wy * (b1.y - a1.y);
            rr[6] = a1.z + wy * (b1.z - a1.z);
            rr[7] = a1.w + wy * (b1.w - a1.w);
            float4 o;
            #define COLLERP(e0,e1,e2,e3,e4) \
                o.x = rr[e0] + wx * (rr[e1] - rr[e0]); \
                o.y = rr[e1] + wx * (rr[e2] - rr[e1]); \
                o.z = rr[e2] + wx * (rr[e3] - rr[e2]); \
                o.w = rr[e3] + wx * (rr[e4] - rr[e3]);
            switch (s) {             // wave-uniform
                case 0: COLLERP(0,1,2,3,4); break;
                case 1: COLLERP(1,2,3,4,5); break;
                case 2: COLLERP(2,3,4,5,6); break;
                default: COLLERP(3,4,5,6,7); break;
            }
            #undef COLLERP
            *(float4*)(outp + (size_t)r * 256) = o;
        }
    } else {
        // -------- edge block: pixels never staged by any strip window --------
        int ch = bid - 6144;         // 0..287
        int c  = ch % 3;
        int nt = ch / 3;
        float tx = thetas[2 * nt];
        float ty = thetas[2 * nt + 1];
        int D = (int)floorf(-tx);
        int E = (int)floorf(-ty);
        int x_lo = (D - 4) & ~3;
        const float4* img4 = (const float4*)(x + ((size_t)nt * CC + c) * HWP);

        // rows never staged: E>0 -> [0,E); E<0 -> [257+E, 256)
        int rlo, rhi;
        if (E > 0)      { rlo = 0; rhi = E > 256 ? 256 : E; }
        else if (E < 0) { rlo = 257 + E; if (rlo < 0) rlo = 0; rhi = 256; }
        else            { rlo = 0; rhi = 0; }
        for (int t = tid; t < (rhi - rlo) * 64; t += 256) {
            float4 v = img4[(rlo + (t >> 6)) * 64 + (t & 63)];
            vmin = fminf(vmin, fminf(fminf(v.x, v.y), fminf(v.z, v.w)));
            vmax = fmaxf(vmax, fmaxf(fmaxf(v.x, v.y), fmaxf(v.z, v.w)));
        }
        // columns never staged, all rows: [0, x_lo) and [x_lo+272, 256)
        int cl = x_lo; if (cl < 0) cl = 0; if (cl > 256) cl = 256;
        int w4l = cl >> 2;
        if (w4l > 0) {
            for (int t = tid; t < 256 * w4l; t += 256) {
                int row = t / w4l;
                int m   = t - row * w4l;
                float4 v = img4[row * 64 + m];
                vmin = fminf(vmin, fminf(fminf(v.x, v.y), fminf(v.z, v.w)));
                vmax = fmaxf(vmax, fmaxf(fmaxf(v.x, v.y), fmaxf(v.z, v.w)));
            }
        }
        int cu = x_lo + 272; if (cu < 0) cu = 0; if (cu > 256) cu = 256;
        int u4 = cu >> 2, w4u = 64 - u4;
        if (w4u > 0) {
            for (int t = tid; t < 256 * w4u; t += 256) {
                int row = t / w4u;
                int m   = u4 + (t - row * w4u);
                float4 v = img4[row * 64 + m];
                vmin = fminf(vmin, fminf(fminf(v.x, v.y), fminf(v.z, v.w)));
                vmax = fmaxf(vmax, fmaxf(fmaxf(v.x, v.y), fmaxf(v.z, v.w)));
            }
        }
        for (int off = 32; off > 0; off >>= 1) {
            vmin = fminf(vmin, __shfl_down(vmin, off));
            vmax = fmaxf(vmax, __shfl_down(vmax, off));
        }
        if ((tid & 63) == 0) { smin[tid >> 6] = vmin; smax[tid >> 6] = vmax; }
        __syncthreads();
        if (tid == 0) {
            part[(ch * NSLOT + 32) * 2]     = fminf(fminf(smin[0], smin[1]), fminf(smin[2], smin[3]));
            part[(ch * NSLOT + 32) * 2 + 1] = fmaxf(fmaxf(smax[0], smax[1]), fmaxf(smax[2], smax[3]));
        }
    }
}

// ============ L1.5: reduce partials -> per-nt scale/bias table (tiny) ============
// One 64-thread block per nt. Lanes 0..32 each own one slot; shfl-reduce.
// Table layout per nt (stride 12 floats):
//   [0..2]=sA[c], [3]=biasA, [4..6]=sB[c], [7]=biasB, [8]=nt2 (int bits)
__global__ __launch_bounds__(64) void k_scale(const float* __restrict__ part,
                                              const int* __restrict__ dates,
                                              float* __restrict__ tbl) {
    int nt   = blockIdx.x;       // 0..95
    int n    = nt / TT;
    int lane = threadIdx.x;      // 0..63

    // argmin |182 - dates| over t (redundant across lanes; trivial cost)
    int bestv = 0x7FFFFFFF, best = 0;
    for (int t = 0; t < TT; ++t) {
        int d = 182 - dates[n * TT + t];
        d = d < 0 ? -d : d;
        if (d < bestv) { bestv = d; best = t; }
    }
    int nt2 = n * TT + best;

    const float w[3] = {0.299f, 0.587f, 0.114f};
    float biasA = 0.f, biasB = 0.f;
    #pragma unroll
    for (int c = 0; c < 3; ++c) {
        float mnA = 1e30f, mxA = -1e30f, mnB = 1e30f, mxB = -1e30f;
        if (lane < NSLOT) {
            int chA = nt * 3 + c, chB = nt2 * 3 + c;
            mnA = part[(chA * NSLOT + lane) * 2];
            mxA = part[(chA * NSLOT + lane) * 2 + 1];
            mnB = part[(chB * NSLOT + lane) * 2];
            mxB = part[(chB * NSLOT + lane) * 2 + 1];
        }
        for (int off = 32; off > 0; off >>= 1) {
            mnA = fminf(mnA, __shfl_down(mnA, off));
            mxA = fmaxf(mxA, __shfl_down(mxA, off));
            mnB = fminf(mnB, __shfl_down(mnB, off));
            mxB = fmaxf(mxB, __shfl_down(mxB, off));
        }
        if (lane == 0) {
            float sA = w[c] / (mxA - mnA + 1e-8f);
            float sB = w[c] / (mxB - mnB + 1e-8f);
            tbl[nt * TBL_STRIDE + c]     = sA;
            tbl[nt * TBL_STRIDE + 4 + c] = sB;
            biasA -= mnA * sA;
            biasB -= mnB * sB;
        }
    }
    if (lane == 0) {
        tbl[nt * TBL_STRIDE + 3] = biasA;
        tbl[nt * TBL_STRIDE + 7] = biasB;
        tbl[nt * TBL_STRIDE + 8] = __int_as_float(nt2);
    }
}

// ============ L2: gray (both x_pairs channels), coefficients from table ============
__global__ __launch_bounds__(256) void k_gray2(const float* __restrict__ x,
                                               const float* __restrict__ tbl,
                                               float* __restrict__ xp) {
    __shared__ float sc[12];
    int bid = blockIdx.x;
    int nt  = bid >> 6;
    int g   = (bid & 63) * 256 + threadIdx.x;

    if (threadIdx.x < 9) sc[threadIdx.x] = tbl[nt * TBL_STRIDE + threadIdx.x];
    __syncthreads();
    float sA0 = sc[0], sA1 = sc[1], sA2 = sc[2], biasA = sc[3];
    float sB0 = sc[4], sB1 = sc[5], sB2 = sc[6], biasB = sc[7];
    int nt2 = __float_as_int(sc[8]);

    const float4* pA0 = (const float4*)(x + ((size_t)nt  * CC + 0) * HWP);
    const float4* pA1 = (const float4*)(x + ((size_t)nt  * CC + 1) * HWP);
    const float4* pA2 = (const float4*)(x + ((size_t)nt  * CC + 2) * HWP);
    const float4* pB0 = (const float4*)(x + ((size_t)nt2 * CC + 0) * HWP);
    const float4* pB1 = (const float4*)(x + ((size_t)nt2 * CC + 1) * HWP);
    const float4* pB2 = (const float4*)(x + ((size_t)nt2 * CC + 2) * HWP);

    float4 v0 = pA0[g], v1 = pA1[g], v2 = pA2[g];
    float4 rA;
    rA.x = v0.x * sA0 + v1.x * sA1 + v2.x * sA2 + biasA;
    rA.y = v0.y * sA0 + v1.y * sA1 + v2.y * sA2 + biasA;
    rA.z = v0.z * sA0 + v1.z * sA1 + v2.z * sA2 + biasA;
    rA.w = v0.w * sA0 + v1.w * sA1 + v2.w * sA2 + biasA;
    ((float4*)(xp + ((size_t)nt * 2) * HWP))[g] = rA;

    float4 u0 = pB0[g], u1 = pB1[g], u2 = pB2[g];   // ~3 MB unique per n -> L2/L3 hot
    float4 rB;
    rB.x = u0.x * sB0 + u1.x * sB1 + u2.x * sB2 + biasB;
    rB.y = u0.y * sB0 + u1.y * sB1 + u2.y * sB2 + biasB;
    rB.z = u0.z * sB0 + u1.z * sB1 + u2.z * sB2 + biasB;
    rB.w = u0.w * sB0 + u1.w * sB1 + u2.w * sB2 + biasB;
    ((float4*)(xp + ((size_t)nt * 2 + 1) * HWP))[g] = rB;
}

extern "C" void kernel_launch(void* const* d_in, const int* in_sizes, int n_in,
                              void* d_out, int out_size, void* d_ws, size_t ws_size,
                              hipStream_t stream) {
    const float* x      = (const float*)d_in[0];
    const int*   dates  = (const int*)d_in[1];
    const float* thetas = (const float*)d_in[2];
    float* out1 = (float*)d_out;                      // (n,t,c,h,w) shifted output
    float* out2 = out1 + (size_t)NT * CC * HWP;       // x_pairs (n,t,2,h,w)
    float* part = (float*)d_ws;                       // [288][33][2] floats
    float* tbl  = part + TBL_OFF;                     // [96][12] floats

    k_shift_mm<<<6432, 256, 0, stream>>>(x, thetas, out1, part);
    k_scale   <<<96,    64, 0, stream>>>(part, dates, tbl);
    k_gray2   <<<6144, 256, 0, stream>>>(x, tbl, out2);
}